// Round 6
// baseline (1600.944 us; speedup 1.0000x reference)
//
#include <hip/hip_runtime.h>
#include <hip/hip_bf16.h>

#define T_LEN 2048
#define BATCH 128
#define DX 64
#define DH 128
#define KF 192

typedef unsigned int u32;

__device__ __forceinline__ float bf_lo(u32 u){ return __uint_as_float(u << 16); }
__device__ __forceinline__ float bf_hi(u32 u){ return __uint_as_float(u & 0xffff0000u); }

template<int CTRL>
__device__ __forceinline__ float dpp_add(float v){
  int r = __builtin_amdgcn_update_dpp(0, __float_as_int(v), CTRL, 0xf, 0xf, true);
  return v + __int_as_float(r);
}
__device__ __forceinline__ float tanh_f(float s){
  float e = __expf(2.0f * s);
  return 1.0f - __fdividef(2.0f, e + 1.0f);
}
__device__ __forceinline__ u32 pk_bf16(float a, float b){
  __hip_bfloat16 ha = __float2bfloat16(a), hb = __float2bfloat16(b);
  u32 ua = *(unsigned short*)&ha, ub = *(unsigned short*)&hb;
  return ua | (ub << 16);
}

// Anti-remat pin: mark values as asm-modified so the allocator cannot re-load
// them from global inside the loop; they must stay in VGPRs.
#define PIN4(V) asm volatile("" : "+v"(V.x), "+v"(V.y), "+v"(V.z), "+v"(V.w))

#define ACC4(S, W0, W1, W2, W3) \
  { float _s = (S); a0 = fmaf(W0, _s, a0); a1 = fmaf(W1, _s, a1); \
    a2 = fmaf(W2, _s, a2); a3 = fmaf(W3, _s, a3); }

// One WG per (batch, direction): 256 WGs x 256 threads (4 waves).
// lane = ks(bits 0-2) | jgl(bits 3-5); jg = wv*8+jgl; thread computes outputs
// j0=jg*4..+3 over k-slice {x[ks*8..+8)} U {h[ks*16..+16)}.
// Weights pinned in VGPRs via asm. Reduction over ks = 3 pure-DPP VALU ops.
// h in LDS dbuf, padded 20-float slices. One barrier/step; x prefetch
// distance-2, issued AFTER the barrier.
__global__ __launch_bounds__(256, 1) void rnn_scan(
    const float* __restrict__ x,      // [T][B][DX]
    const float* __restrict__ Wf,     // [DH][KF]
    const float* __restrict__ bfv,    // [DH]
    __hip_bfloat16* __restrict__ cat) // [T][B][2*DH]
{
  const int wg  = blockIdx.x;
  const int b   = wg >> 1;
  const int dir = wg & 1;
  const int tid = threadIdx.x;
  const int lane = tid & 63;
  const int wv   = tid >> 6;
  const int ks   = lane & 7;
  const int jg   = wv * 8 + (lane >> 3);
  const int j0   = jg * 4;

  __shared__ float hbuf[2][8 * 20];   // slice ks: h[ks*16+m] at [ks*20+m]

  // ---- weights as named float4s, pinned resident ----
  const float* r0 = Wf + (size_t)(j0 + 0) * KF;
  const float* r1 = Wf + (size_t)(j0 + 1) * KF;
  const float* r2 = Wf + (size_t)(j0 + 2) * KF;
  const float* r3 = Wf + (size_t)(j0 + 3) * KF;
  float4 wx00 = *(const float4*)(r0 + ks*8), wx01 = *(const float4*)(r0 + ks*8 + 4);
  float4 wx10 = *(const float4*)(r1 + ks*8), wx11 = *(const float4*)(r1 + ks*8 + 4);
  float4 wx20 = *(const float4*)(r2 + ks*8), wx21 = *(const float4*)(r2 + ks*8 + 4);
  float4 wx30 = *(const float4*)(r3 + ks*8), wx31 = *(const float4*)(r3 + ks*8 + 4);
  float4 wh00 = *(const float4*)(r0 + 64 + ks*16),     wh01 = *(const float4*)(r0 + 64 + ks*16 + 4);
  float4 wh02 = *(const float4*)(r0 + 64 + ks*16 + 8), wh03 = *(const float4*)(r0 + 64 + ks*16 + 12);
  float4 wh10 = *(const float4*)(r1 + 64 + ks*16),     wh11 = *(const float4*)(r1 + 64 + ks*16 + 4);
  float4 wh12 = *(const float4*)(r1 + 64 + ks*16 + 8), wh13 = *(const float4*)(r1 + 64 + ks*16 + 12);
  float4 wh20 = *(const float4*)(r2 + 64 + ks*16),     wh21 = *(const float4*)(r2 + 64 + ks*16 + 4);
  float4 wh22 = *(const float4*)(r2 + 64 + ks*16 + 8), wh23 = *(const float4*)(r2 + 64 + ks*16 + 12);
  float4 wh30 = *(const float4*)(r3 + 64 + ks*16),     wh31 = *(const float4*)(r3 + 64 + ks*16 + 4);
  float4 wh32 = *(const float4*)(r3 + 64 + ks*16 + 8), wh33 = *(const float4*)(r3 + 64 + ks*16 + 12);
  float bb0 = bfv[j0+0], bb1 = bfv[j0+1], bb2 = bfv[j0+2], bb3 = bfv[j0+3];

  PIN4(wx00); PIN4(wx01); PIN4(wx10); PIN4(wx11);
  PIN4(wx20); PIN4(wx21); PIN4(wx30); PIN4(wx31);
  PIN4(wh00); PIN4(wh01); PIN4(wh02); PIN4(wh03);
  PIN4(wh10); PIN4(wh11); PIN4(wh12); PIN4(wh13);
  PIN4(wh20); PIN4(wh21); PIN4(wh22); PIN4(wh23);
  PIN4(wh30); PIN4(wh31); PIN4(wh32); PIN4(wh33);
  asm volatile("" : "+v"(bb0), "+v"(bb1), "+v"(bb2), "+v"(bb3));

  if (tid < 160) hbuf[0][tid] = 0.0f;

#define XPTR(S) (x + ((size_t)(dir ? (T_LEN - 1 - (S)) : (S)) * BATCH + b) * DX + ks * 8)

  float4 qA0, qA1, qB0, qB1;
  { const float4* p = (const float4*)XPTR(0); qA0 = p[0]; qA1 = p[1]; }
  { const float4* p = (const float4*)XPTR(1); qB0 = p[0]; qB1 = p[1]; }

  __hip_bfloat16* outp = cat + ((size_t)(dir ? (T_LEN - 1) : 0) * BATCH + b) * (2 * DH)
                         + dir * DH + j0;
  const ptrdiff_t ostep = dir ? -(ptrdiff_t)(BATCH * 2 * DH) : (ptrdiff_t)(BATCH * 2 * DH);

  int cur = 0;

#define RSTEP(QX0, QX1, TT)                                                    \
{                                                                              \
  float a0 = wx00.x * QX0.x, a1 = wx10.x * QX0.x,                              \
        a2 = wx20.x * QX0.x, a3 = wx30.x * QX0.x;                              \
  ACC4(QX0.y, wx00.y, wx10.y, wx20.y, wx30.y);                                 \
  ACC4(QX0.z, wx00.z, wx10.z, wx20.z, wx30.z);                                 \
  ACC4(QX0.w, wx00.w, wx10.w, wx20.w, wx30.w);                                 \
  ACC4(QX1.x, wx01.x, wx11.x, wx21.x, wx31.x);                                 \
  ACC4(QX1.y, wx01.y, wx11.y, wx21.y, wx31.y);                                 \
  ACC4(QX1.z, wx01.z, wx11.z, wx21.z, wx31.z);                                 \
  ACC4(QX1.w, wx01.w, wx11.w, wx21.w, wx31.w);                                 \
  __syncthreads();                                                             \
  const float4* _hp = (const float4*)&hbuf[cur][ks * 20];                      \
  float4 h0 = _hp[0], h1 = _hp[1], h2 = _hp[2], h3 = _hp[3];                   \
  { int _s = (TT + 2) < T_LEN ? (TT + 2) : (T_LEN - 1);                        \
    const float4* _p = (const float4*)XPTR(_s); QX0 = _p[0]; QX1 = _p[1]; }    \
  ACC4(h0.x, wh00.x, wh10.x, wh20.x, wh30.x);                                  \
  ACC4(h0.y, wh00.y, wh10.y, wh20.y, wh30.y);                                  \
  ACC4(h0.z, wh00.z, wh10.z, wh20.z, wh30.z);                                  \
  ACC4(h0.w, wh00.w, wh10.w, wh20.w, wh30.w);                                  \
  ACC4(h1.x, wh01.x, wh11.x, wh21.x, wh31.x);                                  \
  ACC4(h1.y, wh01.y, wh11.y, wh21.y, wh31.y);                                  \
  ACC4(h1.z, wh01.z, wh11.z, wh21.z, wh31.z);                                  \
  ACC4(h1.w, wh01.w, wh11.w, wh21.w, wh31.w);                                  \
  ACC4(h2.x, wh02.x, wh12.x, wh22.x, wh32.x);                                  \
  ACC4(h2.y, wh02.y, wh12.y, wh22.y, wh32.y);                                  \
  ACC4(h2.z, wh02.z, wh12.z, wh22.z, wh32.z);                                  \
  ACC4(h2.w, wh02.w, wh12.w, wh22.w, wh32.w);                                  \
  ACC4(h3.x, wh03.x, wh13.x, wh23.x, wh33.x);                                  \
  ACC4(h3.y, wh03.y, wh13.y, wh23.y, wh33.y);                                  \
  ACC4(h3.z, wh03.z, wh13.z, wh23.z, wh33.z);                                  \
  ACC4(h3.w, wh03.w, wh13.w, wh23.w, wh33.w);                                  \
  a0 = dpp_add<0xB1>(a0);  a1 = dpp_add<0xB1>(a1);                             \
  a2 = dpp_add<0xB1>(a2);  a3 = dpp_add<0xB1>(a3);                             \
  a0 = dpp_add<0x4E>(a0);  a1 = dpp_add<0x4E>(a1);                             \
  a2 = dpp_add<0x4E>(a2);  a3 = dpp_add<0x4E>(a3);                             \
  a0 = dpp_add<0x141>(a0); a1 = dpp_add<0x141>(a1);                            \
  a2 = dpp_add<0x141>(a2); a3 = dpp_add<0x141>(a3);                            \
  float hn0 = tanh_f(a0 + bb0), hn1 = tanh_f(a1 + bb1);                        \
  float hn2 = tanh_f(a2 + bb2), hn3 = tanh_f(a3 + bb3);                        \
  if ((lane & 7) == 0) {                                                       \
    *(float4*)&hbuf[cur ^ 1][(jg >> 2) * 20 + (jg & 3) * 4] =                  \
        make_float4(hn0, hn1, hn2, hn3);                                       \
    uint2 st; st.x = pk_bf16(hn0, hn1); st.y = pk_bf16(hn2, hn3);              \
    *(uint2*)outp = st;                                                        \
  }                                                                            \
  cur ^= 1; outp += ostep;                                                     \
}

  #pragma unroll 1
  for (int t = 0; t < T_LEN; t += 2) {
    RSTEP(qA0, qA1, t)
    RSTEP(qB0, qB1, t + 1)
  }
#undef RSTEP
#undef XPTR
}

#define FMA4(A, W, S) { A.x = fmaf(S, W.x, A.x); A.y = fmaf(S, W.y, A.y); \
                        A.z = fmaf(S, W.z, A.z); A.w = fmaf(S, W.w, A.w); }
#define UNPK(WA, WB, W0, W1, W2, W3) \
  W0 = make_float4(bf_lo(WA.x), bf_hi(WA.x), bf_lo(WA.y), bf_hi(WA.y)); \
  W1 = make_float4(bf_lo(WA.z), bf_hi(WA.z), bf_lo(WA.w), bf_hi(WA.w)); \
  W2 = make_float4(bf_lo(WB.x), bf_hi(WB.x), bf_lo(WB.y), bf_hi(WB.y)); \
  W3 = make_float4(bf_lo(WB.z), bf_hi(WB.z), bf_lo(WB.w), bf_hi(WB.w));

// Thread = 4 rows x 16 outputs (os = tid&3): each pair of Wo LDS reads feeds
// 4 rows' FMAs (halves per-row LDS traffic vs 2-row version).
__global__ __launch_bounds__(256, 2) void proj_loss(
    const __hip_bfloat16* __restrict__ cat, // [T*B][256]
    const float* __restrict__ Wo,           // [64][256]
    const float* __restrict__ bo,           // [64]
    const float* __restrict__ tg,           // [T*B][64]
    float* __restrict__ out)
{
  __shared__ unsigned short WoT[256][64];   // [k][o] bf16, 32 KiB
  __shared__ float psum[4];
  const int tid = threadIdx.x;
  for (int i = tid; i < 64 * 256; i += 256) {
    int o = i >> 8, k = i & 255;
    __hip_bfloat16 hb = __float2bfloat16(Wo[i]);
    WoT[k][o] = *(unsigned short*)&hb;
  }
  __syncthreads();

  const int os = tid & 3;
  const size_t rowA = (size_t)blockIdx.x * 256 + (size_t)(tid >> 2) * 4;
  const __hip_bfloat16* crA = cat + rowA * 256;

  float4 aA0, aA1, aA2, aA3, aB0, aB1, aB2, aB3;
  float4 aC0, aC1, aC2, aC3, aD0, aD1, aD2, aD3;
  { const float4* bp = (const float4*)(bo + os * 16);
    aA0 = bp[0]; aA1 = bp[1]; aA2 = bp[2]; aA3 = bp[3];
    aB0 = aA0; aB1 = aA1; aB2 = aA2; aB3 = aA3;
    aC0 = aA0; aC1 = aA1; aC2 = aA2; aC3 = aA3;
    aD0 = aA0; aD1 = aA1; aD2 = aA2; aD3 = aA3; }

  #pragma unroll 1
  for (int k8 = 0; k8 < 32; ++k8) {
    uint4 cA = *(const uint4*)(crA + 0 * 256 + k8 * 8);
    uint4 cB = *(const uint4*)(crA + 1 * 256 + k8 * 8);
    uint4 cC = *(const uint4*)(crA + 2 * 256 + k8 * 8);
    uint4 cD = *(const uint4*)(crA + 3 * 256 + k8 * 8);
    const uint4* wbase = (const uint4*)WoT + (size_t)k8 * 64 + os * 2;
#define KSTEP(KK, FA, FB, FC, FD) { \
    uint4 wa = wbase[KK * 8], wb = wbase[KK * 8 + 1]; \
    float4 w0, w1, w2, w3; UNPK(wa, wb, w0, w1, w2, w3); \
    float fa = (FA), fb = (FB), fc = (FC), fd = (FD); \
    FMA4(aA0, w0, fa); FMA4(aA1, w1, fa); FMA4(aA2, w2, fa); FMA4(aA3, w3, fa); \
    FMA4(aB0, w0, fb); FMA4(aB1, w1, fb); FMA4(aB2, w2, fb); FMA4(aB3, w3, fb); \
    FMA4(aC0, w0, fc); FMA4(aC1, w1, fc); FMA4(aC2, w2, fc); FMA4(aC3, w3, fc); \
    FMA4(aD0, w0, fd); FMA4(aD1, w1, fd); FMA4(aD2, w2, fd); FMA4(aD3, w3, fd); }
    KSTEP(0, bf_lo(cA.x), bf_lo(cB.x), bf_lo(cC.x), bf_lo(cD.x))
    KSTEP(1, bf_hi(cA.x), bf_hi(cB.x), bf_hi(cC.x), bf_hi(cD.x))
    KSTEP(2, bf_lo(cA.y), bf_lo(cB.y), bf_lo(cC.y), bf_lo(cD.y))
    KSTEP(3, bf_hi(cA.y), bf_hi(cB.y), bf_hi(cC.y), bf_hi(cD.y))
    KSTEP(4, bf_lo(cA.z), bf_lo(cB.z), bf_lo(cC.z), bf_lo(cD.z))
    KSTEP(5, bf_hi(cA.z), bf_hi(cB.z), bf_hi(cC.z), bf_hi(cD.z))
    KSTEP(6, bf_lo(cA.w), bf_lo(cB.w), bf_lo(cC.w), bf_lo(cD.w))
    KSTEP(7, bf_hi(cA.w), bf_hi(cB.w), bf_hi(cC.w), bf_hi(cD.w))
#undef KSTEP
  }

  float csum = 0.0f;
  const float* tA = tg + rowA * 64;

#define MAX4(V) fmaxf(fmaxf(V.x, V.y), fmaxf(V.z, V.w))
#define EXPS4(V, M) (__expf(V.x - M) + __expf(V.y - M) + __expf(V.z - M) + __expf(V.w - M))
#define LACC(T4, V, L) { csum = fmaf(T4.x, L - V.x, csum); csum = fmaf(T4.y, L - V.y, csum); \
                         csum = fmaf(T4.z, L - V.z, csum); csum = fmaf(T4.w, L - V.w, csum); }
#define ROWLOSS(A0, A1, A2, A3, TPTR) { \
    float m = fmaxf(fmaxf(MAX4(A0), MAX4(A1)), fmaxf(MAX4(A2), MAX4(A3)));     \
    m = fmaxf(m, __shfl_xor(m, 1, 64)); m = fmaxf(m, __shfl_xor(m, 2, 64));    \
    float se = EXPS4(A0, m) + EXPS4(A1, m) + EXPS4(A2, m) + EXPS4(A3, m);      \
    se += __shfl_xor(se, 1, 64); se += __shfl_xor(se, 2, 64);                  \
    float lse = m + __logf(se);                                                \
    const float4* tp = (const float4*)(TPTR + os * 16);                        \
    float4 t0 = tp[0], t1 = tp[1], t2 = tp[2], t3 = tp[3];                     \
    LACC(t0, A0, lse); LACC(t1, A1, lse); LACC(t2, A2, lse); LACC(t3, A3, lse); }

  ROWLOSS(aA0, aA1, aA2, aA3, tA)
  ROWLOSS(aB0, aB1, aB2, aB3, (tA + 64))
  ROWLOSS(aC0, aC1, aC2, aC3, (tA + 128))
  ROWLOSS(aD0, aD1, aD2, aD3, (tA + 192))
#undef ROWLOSS
#undef LACC
#undef EXPS4
#undef MAX4

  #pragma unroll
  for (int off = 32; off; off >>= 1) csum += __shfl_down(csum, off, 64);
  if ((tid & 63) == 0) psum[tid >> 6] = csum;
  __syncthreads();
  if (tid == 0)
    atomicAdd(out, (psum[0] + psum[1] + psum[2] + psum[3]) * (1.0f / BATCH));
}

extern "C" void kernel_launch(void* const* d_in, const int* in_sizes, int n_in,
                              void* d_out, int out_size, void* d_ws, size_t ws_size,
                              hipStream_t stream)
{
  const float* inps = (const float*)d_in[0];
  const float* tg   = (const float*)d_in[1];
  const float* Wf   = (const float*)d_in[2];
  const float* bfv  = (const float*)d_in[3];
  const float* Wo   = (const float*)d_in[4];
  const float* bo   = (const float*)d_in[5];
  float* out = (float*)d_out;

  __hip_bfloat16* cat = (__hip_bfloat16*)d_ws;   // [T][B][2*DH] bf16 = 128 MiB

  (void)hipMemsetAsync(out, 0, sizeof(float), stream);
  rnn_scan<<<BATCH * 2, 256, 0, stream>>>(inps, Wf, bfv, cat);
  proj_loss<<<(T_LEN * BATCH) / 256, 256, 0, stream>>>(cat, Wo, bo, tg, out);
}

// Round 9
// 1226.687 us; speedup vs baseline: 1.3051x; 1.3051x over previous
//
#include <hip/hip_runtime.h>
#include <hip/hip_bf16.h>

#define T_LEN 2048
#define BATCH 128
#define DX 64
#define DH 128
#define KF 192

typedef unsigned int u32;

__device__ __forceinline__ float bf_lo(u32 u){ return __uint_as_float(u << 16); }
__device__ __forceinline__ float bf_hi(u32 u){ return __uint_as_float(u & 0xffff0000u); }

template<int CTRL>
__device__ __forceinline__ float dpp_add(float v){
  int r = __builtin_amdgcn_update_dpp(0, __float_as_int(v), CTRL, 0xf, 0xf, true);
  return v + __int_as_float(r);
}
__device__ __forceinline__ float tanh_f(float s){
  float e = __expf(2.0f * s);
  return 1.0f - __fdividef(2.0f, e + 1.0f);
}
__device__ __forceinline__ u32 pk_bf16(float a, float b){
  __hip_bfloat16 ha = __float2bfloat16(a), hb = __float2bfloat16(b);
  u32 ua = *(unsigned short*)&ha, ub = *(unsigned short*)&hb;
  return ua | (ub << 16);
}

// Anti-remat pin: values become asm-defined; cannot be re-loaded from global.
#define PIN4(V) asm volatile("" : "+v"(V.x), "+v"(V.y), "+v"(V.z), "+v"(V.w))

#define ACC4(S, W0, W1, W2, W3) \
  { float _s = (S); a0 = fmaf(W0, _s, a0); a1 = fmaf(W1, _s, a1); \
    a2 = fmaf(W2, _s, a2); a3 = fmaf(W3, _s, a3); }

// One WG per (batch, direction): 256 WGs x 256 threads (4 waves = 1 wave/EU).
// amdgpu_waves_per_eu(1,1): min=max=1 wave/EU -> 512-VGPR budget, so the 96
// weight floats stay resident (R6 showed launch_bounds min alone leaves the
// allocator targeting 8 waves/EU = 64 VGPRs and spilling).
// lane = ks(bits 0-2) | jgl(bits 3-5); thread computes outputs j0=jg*4..+3
// over k-slice {x[ks*8..+8)} U {h[ks*16..+16)}. Step order: barrier ->
// ds_read h (latency hidden under x-FMAs) -> x-FMAs -> prefetch x(t+2) ->
// h-FMAs -> 3xDPP reduce -> tanh -> LDS/global write.
__global__ __launch_bounds__(256)
__attribute__((amdgpu_waves_per_eu(1, 1)))
void rnn_scan(
    const float* __restrict__ x,      // [T][B][DX]
    const float* __restrict__ Wf,     // [DH][KF]
    const float* __restrict__ bfv,    // [DH]
    __hip_bfloat16* __restrict__ cat) // [T][B][2*DH]
{
  const int wg  = blockIdx.x;
  const int b   = wg >> 1;
  const int dir = wg & 1;
  const int tid = threadIdx.x;
  const int lane = tid & 63;
  const int wv   = tid >> 6;
  const int ks   = lane & 7;
  const int jg   = wv * 8 + (lane >> 3);
  const int j0   = jg * 4;

  __shared__ float hbuf[2][8 * 20];   // slice ks: h[ks*16+m] at [ks*20+m]

  // ---- weights as named float4s, pinned resident ----
  const float* r0 = Wf + (size_t)(j0 + 0) * KF;
  const float* r1 = Wf + (size_t)(j0 + 1) * KF;
  const float* r2 = Wf + (size_t)(j0 + 2) * KF;
  const float* r3 = Wf + (size_t)(j0 + 3) * KF;
  float4 wx00 = *(const float4*)(r0 + ks*8), wx01 = *(const float4*)(r0 + ks*8 + 4);
  float4 wx10 = *(const float4*)(r1 + ks*8), wx11 = *(const float4*)(r1 + ks*8 + 4);
  float4 wx20 = *(const float4*)(r2 + ks*8), wx21 = *(const float4*)(r2 + ks*8 + 4);
  float4 wx30 = *(const float4*)(r3 + ks*8), wx31 = *(const float4*)(r3 + ks*8 + 4);
  float4 wh00 = *(const float4*)(r0 + 64 + ks*16),     wh01 = *(const float4*)(r0 + 64 + ks*16 + 4);
  float4 wh02 = *(const float4*)(r0 + 64 + ks*16 + 8), wh03 = *(const float4*)(r0 + 64 + ks*16 + 12);
  float4 wh10 = *(const float4*)(r1 + 64 + ks*16),     wh11 = *(const float4*)(r1 + 64 + ks*16 + 4);
  float4 wh12 = *(const float4*)(r1 + 64 + ks*16 + 8), wh13 = *(const float4*)(r1 + 64 + ks*16 + 12);
  float4 wh20 = *(const float4*)(r2 + 64 + ks*16),     wh21 = *(const float4*)(r2 + 64 + ks*16 + 4);
  float4 wh22 = *(const float4*)(r2 + 64 + ks*16 + 8), wh23 = *(const float4*)(r2 + 64 + ks*16 + 12);
  float4 wh30 = *(const float4*)(r3 + 64 + ks*16),     wh31 = *(const float4*)(r3 + 64 + ks*16 + 4);
  float4 wh32 = *(const float4*)(r3 + 64 + ks*16 + 8), wh33 = *(const float4*)(r3 + 64 + ks*16 + 12);
  float bb0 = bfv[j0+0], bb1 = bfv[j0+1], bb2 = bfv[j0+2], bb3 = bfv[j0+3];

  PIN4(wx00); PIN4(wx01); PIN4(wx10); PIN4(wx11);
  PIN4(wx20); PIN4(wx21); PIN4(wx30); PIN4(wx31);
  PIN4(wh00); PIN4(wh01); PIN4(wh02); PIN4(wh03);
  PIN4(wh10); PIN4(wh11); PIN4(wh12); PIN4(wh13);
  PIN4(wh20); PIN4(wh21); PIN4(wh22); PIN4(wh23);
  PIN4(wh30); PIN4(wh31); PIN4(wh32); PIN4(wh33);
  asm volatile("" : "+v"(bb0), "+v"(bb1), "+v"(bb2), "+v"(bb3));

  if (tid < 160) hbuf[0][tid] = 0.0f;

#define XPTR(S) (x + ((size_t)(dir ? (T_LEN - 1 - (S)) : (S)) * BATCH + b) * DX + ks * 8)

  float4 qA0, qA1, qB0, qB1;
  { const float4* p = (const float4*)XPTR(0); qA0 = p[0]; qA1 = p[1]; }
  { const float4* p = (const float4*)XPTR(1); qB0 = p[0]; qB1 = p[1]; }

  __hip_bfloat16* outp = cat + ((size_t)(dir ? (T_LEN - 1) : 0) * BATCH + b) * (2 * DH)
                         + dir * DH + j0;
  const ptrdiff_t ostep = dir ? -(ptrdiff_t)(BATCH * 2 * DH) : (ptrdiff_t)(BATCH * 2 * DH);

  int cur = 0;

#define RSTEP(QX0, QX1, TT)                                                    \
{                                                                              \
  __syncthreads();                                                             \
  const float4* _hp = (const float4*)&hbuf[cur][ks * 20];                      \
  float4 h0 = _hp[0], h1 = _hp[1], h2 = _hp[2], h3 = _hp[3];                   \
  float a0 = wx00.x * QX0.x, a1 = wx10.x * QX0.x,                              \
        a2 = wx20.x * QX0.x, a3 = wx30.x * QX0.x;                              \
  ACC4(QX0.y, wx00.y, wx10.y, wx20.y, wx30.y);                                 \
  ACC4(QX0.z, wx00.z, wx10.z, wx20.z, wx30.z);                                 \
  ACC4(QX0.w, wx00.w, wx10.w, wx20.w, wx30.w);                                 \
  ACC4(QX1.x, wx01.x, wx11.x, wx21.x, wx31.x);                                 \
  ACC4(QX1.y, wx01.y, wx11.y, wx21.y, wx31.y);                                 \
  ACC4(QX1.z, wx01.z, wx11.z, wx21.z, wx31.z);                                 \
  ACC4(QX1.w, wx01.w, wx11.w, wx21.w, wx31.w);                                 \
  { int _s = (TT + 2) < T_LEN ? (TT + 2) : (T_LEN - 1);                        \
    const float4* _p = (const float4*)XPTR(_s); QX0 = _p[0]; QX1 = _p[1]; }    \
  ACC4(h0.x, wh00.x, wh10.x, wh20.x, wh30.x);                                  \
  ACC4(h0.y, wh00.y, wh10.y, wh20.y, wh30.y);                                  \
  ACC4(h0.z, wh00.z, wh10.z, wh20.z, wh30.z);                                  \
  ACC4(h0.w, wh00.w, wh10.w, wh20.w, wh30.w);                                  \
  ACC4(h1.x, wh01.x, wh11.x, wh21.x, wh31.x);                                  \
  ACC4(h1.y, wh01.y, wh11.y, wh21.y, wh31.y);                                  \
  ACC4(h1.z, wh01.z, wh11.z, wh21.z, wh31.z);                                  \
  ACC4(h1.w, wh01.w, wh11.w, wh21.w, wh31.w);                                  \
  ACC4(h2.x, wh02.x, wh12.x, wh22.x, wh32.x);                                  \
  ACC4(h2.y, wh02.y, wh12.y, wh22.y, wh32.y);                                  \
  ACC4(h2.z, wh02.z, wh12.z, wh22.z, wh32.z);                                  \
  ACC4(h2.w, wh02.w, wh12.w, wh22.w, wh32.w);                                  \
  ACC4(h3.x, wh03.x, wh13.x, wh23.x, wh33.x);                                  \
  ACC4(h3.y, wh03.y, wh13.y, wh23.y, wh33.y);                                  \
  ACC4(h3.z, wh03.z, wh13.z, wh23.z, wh33.z);                                  \
  ACC4(h3.w, wh03.w, wh13.w, wh23.w, wh33.w);                                  \
  a0 = dpp_add<0xB1>(a0);  a1 = dpp_add<0xB1>(a1);                             \
  a2 = dpp_add<0xB1>(a2);  a3 = dpp_add<0xB1>(a3);                             \
  a0 = dpp_add<0x4E>(a0);  a1 = dpp_add<0x4E>(a1);                             \
  a2 = dpp_add<0x4E>(a2);  a3 = dpp_add<0x4E>(a3);                             \
  a0 = dpp_add<0x141>(a0); a1 = dpp_add<0x141>(a1);                            \
  a2 = dpp_add<0x141>(a2); a3 = dpp_add<0x141>(a3);                            \
  float hn0 = tanh_f(a0 + bb0), hn1 = tanh_f(a1 + bb1);                        \
  float hn2 = tanh_f(a2 + bb2), hn3 = tanh_f(a3 + bb3);                        \
  if ((lane & 7) == 0) {                                                       \
    *(float4*)&hbuf[cur ^ 1][(jg >> 2) * 20 + (jg & 3) * 4] =                  \
        make_float4(hn0, hn1, hn2, hn3);                                       \
    uint2 st; st.x = pk_bf16(hn0, hn1); st.y = pk_bf16(hn2, hn3);              \
    *(uint2*)outp = st;                                                        \
  }                                                                            \
  cur ^= 1; outp += ostep;                                                     \
}

  #pragma unroll 1
  for (int t = 0; t < T_LEN; t += 2) {
    RSTEP(qA0, qA1, t)
    RSTEP(qB0, qB1, t + 1)
  }
#undef RSTEP
#undef XPTR
}

#define FMA4(A, W, S) { A.x = fmaf(S, W.x, A.x); A.y = fmaf(S, W.y, A.y); \
                        A.z = fmaf(S, W.z, A.z); A.w = fmaf(S, W.w, A.w); }
#define UNPK(WA, WB, W0, W1, W2, W3) \
  W0 = make_float4(bf_lo(WA.x), bf_hi(WA.x), bf_lo(WA.y), bf_hi(WA.y)); \
  W1 = make_float4(bf_lo(WA.z), bf_hi(WA.z), bf_lo(WA.w), bf_hi(WA.w)); \
  W2 = make_float4(bf_lo(WB.x), bf_hi(WB.x), bf_lo(WB.y), bf_hi(WB.y)); \
  W3 = make_float4(bf_lo(WB.z), bf_hi(WB.z), bf_lo(WB.w), bf_hi(WB.w));

// Thread = 4 rows x 16 outputs (os = tid&3); cat rows prefetched distance-1
// so each k8 iteration's global loads overlap the previous one's FMAs.
__global__ __launch_bounds__(256, 2) void proj_loss(
    const __hip_bfloat16* __restrict__ cat, // [T*B][256]
    const float* __restrict__ Wo,           // [64][256]
    const float* __restrict__ bo,           // [64]
    const float* __restrict__ tg,           // [T*B][64]
    float* __restrict__ out)
{
  __shared__ unsigned short WoT[256][64];   // [k][o] bf16, 32 KiB
  __shared__ float psum[4];
  const int tid = threadIdx.x;
  for (int i = tid; i < 64 * 256; i += 256) {
    int o = i >> 8, k = i & 255;
    __hip_bfloat16 hb = __float2bfloat16(Wo[i]);
    WoT[k][o] = *(unsigned short*)&hb;
  }
  __syncthreads();

  const int os = tid & 3;
  const size_t rowA = (size_t)blockIdx.x * 256 + (size_t)(tid >> 2) * 4;
  const __hip_bfloat16* crA = cat + rowA * 256;

  float4 aA0, aA1, aA2, aA3, aB0, aB1, aB2, aB3;
  float4 aC0, aC1, aC2, aC3, aD0, aD1, aD2, aD3;
  { const float4* bp = (const float4*)(bo + os * 16);
    aA0 = bp[0]; aA1 = bp[1]; aA2 = bp[2]; aA3 = bp[3];
    aB0 = aA0; aB1 = aA1; aB2 = aA2; aB3 = aA3;
    aC0 = aA0; aC1 = aA1; aC2 = aA2; aC3 = aA3;
    aD0 = aA0; aD1 = aA1; aD2 = aA2; aD3 = aA3; }

  uint4 cA = *(const uint4*)(crA + 0 * 256);
  uint4 cB = *(const uint4*)(crA + 1 * 256);
  uint4 cC = *(const uint4*)(crA + 2 * 256);
  uint4 cD = *(const uint4*)(crA + 3 * 256);

  #pragma unroll 1
  for (int k8 = 0; k8 < 32; ++k8) {
    const int kn = (k8 + 1) & 31;             // wraps to 0 on last iter (harmless)
    uint4 nA = *(const uint4*)(crA + 0 * 256 + kn * 8);
    uint4 nB = *(const uint4*)(crA + 1 * 256 + kn * 8);
    uint4 nC = *(const uint4*)(crA + 2 * 256 + kn * 8);
    uint4 nD = *(const uint4*)(crA + 3 * 256 + kn * 8);
    const uint4* wbase = (const uint4*)WoT + (size_t)k8 * 64 + os * 2;
#define KSTEP(KK, FA, FB, FC, FD) { \
    uint4 wa = wbase[KK * 8], wb = wbase[KK * 8 + 1]; \
    float4 w0, w1, w2, w3; UNPK(wa, wb, w0, w1, w2, w3); \
    float fa = (FA), fb = (FB), fc = (FC), fd = (FD); \
    FMA4(aA0, w0, fa); FMA4(aA1, w1, fa); FMA4(aA2, w2, fa); FMA4(aA3, w3, fa); \
    FMA4(aB0, w0, fb); FMA4(aB1, w1, fb); FMA4(aB2, w2, fb); FMA4(aB3, w3, fb); \
    FMA4(aC0, w0, fc); FMA4(aC1, w1, fc); FMA4(aC2, w2, fc); FMA4(aC3, w3, fc); \
    FMA4(aD0, w0, fd); FMA4(aD1, w1, fd); FMA4(aD2, w2, fd); FMA4(aD3, w3, fd); }
    KSTEP(0, bf_lo(cA.x), bf_lo(cB.x), bf_lo(cC.x), bf_lo(cD.x))
    KSTEP(1, bf_hi(cA.x), bf_hi(cB.x), bf_hi(cC.x), bf_hi(cD.x))
    KSTEP(2, bf_lo(cA.y), bf_lo(cB.y), bf_lo(cC.y), bf_lo(cD.y))
    KSTEP(3, bf_hi(cA.y), bf_hi(cB.y), bf_hi(cC.y), bf_hi(cD.y))
    KSTEP(4, bf_lo(cA.z), bf_lo(cB.z), bf_lo(cC.z), bf_lo(cD.z))
    KSTEP(5, bf_hi(cA.z), bf_hi(cB.z), bf_hi(cC.z), bf_hi(cD.z))
    KSTEP(6, bf_lo(cA.w), bf_lo(cB.w), bf_lo(cC.w), bf_lo(cD.w))
    KSTEP(7, bf_hi(cA.w), bf_hi(cB.w), bf_hi(cC.w), bf_hi(cD.w))
#undef KSTEP
    cA = nA; cB = nB; cC = nC; cD = nD;
  }

  float csum = 0.0f;
  const float* tA = tg + rowA * 64;

#define MAX4(V) fmaxf(fmaxf(V.x, V.y), fmaxf(V.z, V.w))
#define EXPS4(V, M) (__expf(V.x - M) + __expf(V.y - M) + __expf(V.z - M) + __expf(V.w - M))
#define LACC(T4, V, L) { csum = fmaf(T4.x, L - V.x, csum); csum = fmaf(T4.y, L - V.y, csum); \
                         csum = fmaf(T4.z, L - V.z, csum); csum = fmaf(T4.w, L - V.w, csum); }
#define ROWLOSS(A0, A1, A2, A3, TPTR) { \
    float m = fmaxf(fmaxf(MAX4(A0), MAX4(A1)), fmaxf(MAX4(A2), MAX4(A3)));     \
    m = fmaxf(m, __shfl_xor(m, 1, 64)); m = fmaxf(m, __shfl_xor(m, 2, 64));    \
    float se = EXPS4(A0, m) + EXPS4(A1, m) + EXPS4(A2, m) + EXPS4(A3, m);      \
    se += __shfl_xor(se, 1, 64); se += __shfl_xor(se, 2, 64);                  \
    float lse = m + __logf(se);                                                \
    const float4* tp = (const float4*)(TPTR + os * 16);                        \
    float4 t0 = tp[0], t1 = tp[1], t2 = tp[2], t3 = tp[3];                     \
    LACC(t0, A0, lse); LACC(t1, A1, lse); LACC(t2, A2, lse); LACC(t3, A3, lse); }

  ROWLOSS(aA0, aA1, aA2, aA3, tA)
  ROWLOSS(aB0, aB1, aB2, aB3, (tA + 64))
  ROWLOSS(aC0, aC1, aC2, aC3, (tA + 128))
  ROWLOSS(aD0, aD1, aD2, aD3, (tA + 192))
#undef ROWLOSS
#undef LACC
#undef EXPS4
#undef MAX4

  #pragma unroll
  for (int off = 32; off; off >>= 1) csum += __shfl_down(csum, off, 64);
  if ((tid & 63) == 0) psum[tid >> 6] = csum;
  __syncthreads();
  if (tid == 0)
    atomicAdd(out, (psum[0] + psum[1] + psum[2] + psum[3]) * (1.0f / BATCH));
}

extern "C" void kernel_launch(void* const* d_in, const int* in_sizes, int n_in,
                              void* d_out, int out_size, void* d_ws, size_t ws_size,
                              hipStream_t stream)
{
  const float* inps = (const float*)d_in[0];
  const float* tg   = (const float*)d_in[1];
  const float* Wf   = (const float*)d_in[2];
  const float* bfv  = (const float*)d_in[3];
  const float* Wo   = (const float*)d_in[4];
  const float* bo   = (const float*)d_in[5];
  float* out = (float*)d_out;

  __hip_bfloat16* cat = (__hip_bfloat16*)d_ws;   // [T][B][2*DH] bf16 = 128 MiB

  (void)hipMemsetAsync(out, 0, sizeof(float), stream);
  rnn_scan<<<BATCH * 2, 256, 0, stream>>>(inps, Wf, bfv, cat);
  proj_loss<<<(T_LEN * BATCH) / 256, 256, 0, stream>>>(cat, Wo, bo, tg, out);
}